// Round 1
// baseline (1015.235 us; speedup 1.0000x reference)
//
#include <hip/hip_runtime.h>
#include <hip/hip_bf16.h>
#include <math.h>

#define BATCH 32
#define CDIM  128
#define NTOT  4096
#define HEADS 4
#define DH    32

// kernel 1 chunking
#define NCH1 16
#define CH1  (NTOT / NCH1)   // 256 columns per workgroup
#define TN1  32              // subtile width
// kernel 3 chunking
#define NCH3 16
#define CH3  (NTOT / NCH3)   // 256
#define TN3  64

// ws layout (float offsets)
#define PC_OFF  0
#define PC_SIZE (BATCH * HEADS * NCH1 * DH * DH)   // 2,097,152 floats
#define PS_OFF  (PC_OFF + PC_SIZE)
#define PS_SIZE (BATCH * HEADS * NCH1 * DH)        // 65,536 floats
#define M_OFF   (PS_OFF + PS_SIZE)
#define M_SIZE  (BATCH * CDIM * CDIM)              // 524,288 floats

// ---------------------------------------------------------------------------
// K1: per (batch b, chunk j): KV = W_kv @ x[:, chunk]; partial softmax stats
//     s[d] = sum_n exp(k[d,n]);  C[d,e] = sum_n exp(k[d,n]) * v[e,n]
// block = 256 threads = 4 waves; wave w owns head w.
// ---------------------------------------------------------------------------
__global__ __launch_bounds__(256)
void k1_partial(const float* __restrict__ x, const float* __restrict__ wqkv,
                float* __restrict__ ws) {
    __shared__ float xs[CDIM][TN1];             // 16 KB
    __shared__ float ekT[HEADS][TN1][DH + 1];   // exp(K), transposed + pad, 16.9 KB
    __shared__ float vT[HEADS][DH][TN1];        // V, [e][col], 16 KB

    const int j    = blockIdx.x;
    const int b    = blockIdx.y;
    const int tid  = threadIdx.x;
    const int lane = tid & 63;
    const int h    = __builtin_amdgcn_readfirstlane(tid >> 6);  // head = wave
    const int col  = lane & 31;
    const int half = lane >> 5;        // 0 -> K rows, 1 -> V rows
    const int dC   = lane >> 1;        // phase-B C-row owned by this lane
    const int e0   = (lane & 1) * 16;  // phase-B e-range start

    float Cacc[16];
#pragma unroll
    for (int i = 0; i < 16; ++i) Cacc[i] = 0.f;
    float sacc = 0.f;

    // K split = rows 128..255, V split = rows 256..383 of w_qkv
    const float* Wbase = wqkv + ((size_t)((1 + half) * CDIM + h * DH)) * CDIM;
    const int n0 = j * CH1;

    for (int it = 0; it < CH1 / TN1; ++it) {
        // ---- stage x subtile (all threads) ----
        {
            const int c4 = (tid & 7) * 4;
            const int r0 = tid >> 3;  // 32 rows per pass
            const float* xp = x + (size_t)b * CDIM * NTOT + n0 + it * TN1 + c4;
#pragma unroll
            for (int rr = 0; rr < CDIM; rr += 32) {
                const float4 v4 =
                    *reinterpret_cast<const float4*>(xp + (size_t)(rr + r0) * NTOT);
                *reinterpret_cast<float4*>(&xs[rr + r0][c4]) = v4;
            }
        }
        __syncthreads();  // xs ready

        // ---- phase A: y[d] = W_row[d,:] . xs[:, col] ----
        float y[DH];
#pragma unroll
        for (int d = 0; d < DH; ++d) y[d] = 0.f;
        for (int cb = 0; cb < CDIM; cb += 16) {
            float xc[16];
#pragma unroll
            for (int i = 0; i < 16; ++i) xc[i] = xs[cb + i][col];
#pragma unroll
            for (int d = 0; d < DH; ++d) {
                const float* w = Wbase + d * CDIM + cb;
                float a0 = 0.f;
#pragma unroll
                for (int i = 0; i < 16; ++i) a0 = fmaf(w[i], xc[i], a0);
                y[d] += a0;
            }
        }
        if (half == 0) {
#pragma unroll
            for (int d = 0; d < DH; ++d) ekT[h][col][d] = __expf(y[d]);
        } else {
#pragma unroll
            for (int d = 0; d < DH; ++d) vT[h][d][col] = y[d];
        }
        __syncthreads();  // cross-lane LDS dependency within wave needs a fence

        // ---- phase B: accumulate C[dC][e0..e0+15], s[d] ----
#pragma unroll 2
        for (int cc = 0; cc < TN1; ++cc) {
            const float kk = ekT[h][cc][dC];
            sacc += ekT[h][cc][lane & 31];  // only lanes<32 persist this
#pragma unroll
            for (int jj = 0; jj < 16; ++jj)
                Cacc[jj] = fmaf(kk, vT[h][e0 + jj][cc], Cacc[jj]);
        }
        __syncthreads();  // all waves done with xs/kv before next iteration
    }

    // ---- write partials ----
    {
        float* pC = ws + PC_OFF +
                    (size_t)((b * HEADS + h) * NCH1 + j) * (DH * DH) + dC * DH + e0;
#pragma unroll
        for (int jj = 0; jj < 16; ++jj) pC[jj] = Cacc[jj];
        if (lane < DH)
            ws[PS_OFF + (size_t)((b * HEADS + h) * NCH1 + j) * DH + lane] = sacc;
    }
}

// ---------------------------------------------------------------------------
// K2: merge partials -> context; M[b] = W_out . BD(context^T) . W_q
// grid = 32 (one wg per batch), block = 256
// ---------------------------------------------------------------------------
__global__ __launch_bounds__(256)
void k2_buildM(const float* __restrict__ wqkv, const float* __restrict__ wout,
               float* __restrict__ ws) {
    const int b   = blockIdx.x;
    const int tid = threadIdx.x;
    __shared__ float stot[DH];
    __shared__ float ctx[DH][DH];
    __shared__ float G[CDIM][DH + 1];

    float Macc[64];
#pragma unroll
    for (int i = 0; i < 64; ++i) Macc[i] = 0.f;
    const int o    = tid >> 1;
    const int half = tid & 1;

    for (int h = 0; h < HEADS; ++h) {
        __syncthreads();  // protect ctx/G/stot from previous head's readers
        if (tid < DH) {
            float s = 0.f;
            for (int jj = 0; jj < NCH1; ++jj)
                s += ws[PS_OFF + (size_t)((b * HEADS + h) * NCH1 + jj) * DH + tid];
            stot[tid] = s;
        }
        __syncthreads();
        {
            const int base = (b * HEADS + h) * NCH1;
#pragma unroll
            for (int k = 0; k < 4; ++k) {
                const int idx = tid + 256 * k;
                float c = 0.f;
                for (int jj = 0; jj < NCH1; ++jj)
                    c += ws[PC_OFF + (size_t)(base + jj) * (DH * DH) + idx];
                ctx[idx >> 5][idx & 31] = c / stot[idx >> 5];
            }
        }
        __syncthreads();
        // G[o][d] = sum_e w_out[o, h*32+e] * ctx[d][e]
        {
#pragma unroll
            for (int dd = 0; dd < 16; ++dd) {
                const int d = half * 16 + dd;
                float g = 0.f;
#pragma unroll
                for (int e = 0; e < DH; ++e)
                    g = fmaf(wout[o * CDIM + h * DH + e], ctx[d][e], g);
                G[o][d] = g;
            }
        }
        __syncthreads();
        // Macc[cc] += sum_d G[o][d] * w_q[h*32+d, c0+cc]
        {
            const int c0 = half * 64;
            for (int d = 0; d < DH; ++d) {
                const float gv = G[o][d];
                const float* wq = wqkv + (size_t)(h * DH + d) * CDIM + c0;
#pragma unroll
                for (int cc = 0; cc < 64; ++cc)
                    Macc[cc] = fmaf(gv, wq[cc], Macc[cc]);
            }
        }
    }
    float* M = ws + M_OFF + (size_t)b * CDIM * CDIM + o * CDIM + half * 64;
#pragma unroll
    for (int cc = 0; cc < 64; ++cc) M[cc] = Macc[cc];
}

// ---------------------------------------------------------------------------
// K3: final[b] = M[b] @ x[b] + b_out
// grid (NCH3, BATCH), block 256; wave w owns output rows w*32..w*32+31
// ---------------------------------------------------------------------------
__global__ __launch_bounds__(256)
void k3_final(const float* __restrict__ x, const float* __restrict__ bout,
              const float* __restrict__ ws, float* __restrict__ out) {
    __shared__ float xs[CDIM][TN3];  // 32 KB
    const int j    = blockIdx.x;
    const int b    = blockIdx.y;
    const int tid  = threadIdx.x;
    const int lane = tid & 63;
    const int o0   = __builtin_amdgcn_readfirstlane(tid >> 6) * 32;
    const float* M = ws + M_OFF + (size_t)b * CDIM * CDIM;

    for (int it = 0; it < CH3 / TN3; ++it) {
        const int n0 = j * CH3 + it * TN3;
        {
            const int c4 = (tid & 15) * 4;
            const int r0 = tid >> 4;  // 16 rows per pass
#pragma unroll
            for (int rr = 0; rr < CDIM; rr += 16) {
                const float4 v4 = *reinterpret_cast<const float4*>(
                    x + ((size_t)b * CDIM + rr + r0) * NTOT + n0 + c4);
                *reinterpret_cast<float4*>(&xs[rr + r0][c4]) = v4;
            }
        }
        __syncthreads();
        float y[32];
#pragma unroll
        for (int o = 0; o < 32; ++o) y[o] = 0.f;
        for (int cb = 0; cb < CDIM; cb += 16) {
            float xc[16];
#pragma unroll
            for (int i = 0; i < 16; ++i) xc[i] = xs[cb + i][lane];
#pragma unroll
            for (int o = 0; o < 32; ++o) {
                const float* m = M + (size_t)(o0 + o) * CDIM + cb;
                float a = 0.f;
#pragma unroll
                for (int i = 0; i < 16; ++i) a = fmaf(m[i], xc[i], a);
                y[o] += a;
            }
        }
#pragma unroll
        for (int o = 0; o < 32; ++o) {
            out[((size_t)b * CDIM + o0 + o) * NTOT + n0 + lane] = y[o] + bout[o0 + o];
        }
        __syncthreads();  // xs reuse next iteration
    }
}

extern "C" void kernel_launch(void* const* d_in, const int* in_sizes, int n_in,
                              void* d_out, int out_size, void* d_ws, size_t ws_size,
                              hipStream_t stream) {
    const float* x    = (const float*)d_in[0];
    const float* wqkv = (const float*)d_in[1];
    const float* wout = (const float*)d_in[2];
    const float* bout = (const float*)d_in[3];
    float* out = (float*)d_out;
    float* ws  = (float*)d_ws;

    k1_partial<<<dim3(NCH1, BATCH), 256, 0, stream>>>(x, wqkv, ws);
    k2_buildM<<<dim3(BATCH), 256, 0, stream>>>(wqkv, wout, ws);
    k3_final<<<dim3(NCH3, BATCH), 256, 0, stream>>>(x, bout, ws, out);
}

// Round 4
// 367.098 us; speedup vs baseline: 2.7656x; 2.7656x over previous
//
#include <hip/hip_runtime.h>
#include <hip/hip_bf16.h>
#include <math.h>

#define BATCH 32
#define CDIM  128
#define NTOT  4096
#define NCH   16           // chunks per batch (k1/k3 grid.x)
#define CHN   256          // n per block
#define TN    64           // n per subtile

typedef __attribute__((ext_vector_type(4))) float f32x4;
typedef __attribute__((ext_vector_type(8))) short s16x8;

// ---- ws layout (float offsets) ----
#define PC_OFF  0
#define PC_SIZE (BATCH * 4 * NCH * 32 * 32)   // partial C2[e][d], 2,097,152 f
#define PS_OFF  (PC_OFF + PC_SIZE)
#define PS_SIZE (BATCH * 4 * NCH * 32)        // partial s[d], 65,536 f
#define WBF_OFF (PS_OFF + PS_SIZE)            // w_qkv bf16: 49,152 u16 = 24,576 f
#define MBF_OFF (WBF_OFF + 24576)             // M bf16: 524,288 u16 = 262,144 f

static __device__ __forceinline__ unsigned short f2bf(float f) {
    return __builtin_bit_cast(unsigned short, __float2bfloat16(f));
}
static __device__ __forceinline__ unsigned int pack2(float a, float b) {
    return (unsigned int)f2bf(a) | ((unsigned int)f2bf(b) << 16);
}
static __device__ __forceinline__ s16x8 ld_frag_lds(const unsigned int* xsd, int d0) {
    int4 t;
    t.x = (int)xsd[d0]; t.y = (int)xsd[d0 + 1];
    t.z = (int)xsd[d0 + 2]; t.w = (int)xsd[d0 + 3];
    return __builtin_bit_cast(s16x8, t);
}

// Stage a 128c x 64n fp32 tile -> LDS bf16 transposed [n][c], 65 dwords/row.
// Thread t: n-quad = (t&15)*4, c-pair = 2*(t>>4) + 32p. Coalesced float4 loads,
// paired-c b32 writes (bank = 4m + (l>>4) + const -> ~2-way, free).
static __device__ __forceinline__ void stage_xT(const float* __restrict__ xc,
                                                unsigned int* __restrict__ xsd,
                                                int tid) {
    const int m  = tid & 15;
    const int cg = tid >> 4;
#pragma unroll
    for (int p = 0; p < 4; ++p) {
        const int c = 2 * cg + 32 * p;
        const f32x4 a0 = *reinterpret_cast<const f32x4*>(xc + (size_t)c * NTOT + 4 * m);
        const f32x4 a1 = *reinterpret_cast<const f32x4*>(xc + (size_t)(c + 1) * NTOT + 4 * m);
#pragma unroll
        for (int jj = 0; jj < 4; ++jj)
            xsd[(4 * m + jj) * 65 + (c >> 1)] = pack2(a0[jj], a1[jj]);
    }
}

// ---------------------------------------------------------------------------
// k0: convert w_qkv to bf16 in ws
// ---------------------------------------------------------------------------
__global__ void k0_wcvt(const float* __restrict__ wqkv, float* __restrict__ ws) {
    const int i = blockIdx.x * 256 + threadIdx.x;
    unsigned short* wbf = (unsigned short*)(ws + WBF_OFF);
    if (i < 384 * CDIM) wbf[i] = f2bf(wqkv[i]);
}

// ---------------------------------------------------------------------------
// k1: per (chunk j, batch b): KV = W_kv @ x_chunk (MFMA), exp, partial s and
//     C2[e][d] = sum_n v[e,n]*exp(k[d,n]) (MFMA, operands from padded LDS).
// 4 waves: waves 0-1 own K rows (heads 0-3), waves 2-3 own V rows.
// Context MFMA: wave w handles head w.
// ---------------------------------------------------------------------------
__global__ __launch_bounds__(256, 2)
void k1_ctx(const float* __restrict__ x, const unsigned short* __restrict__ wbf,
            float* __restrict__ ws) {
    __shared__ __attribute__((aligned(16))) unsigned short xsT[64 * 130];   // 16.6 KB
    __shared__ __attribute__((aligned(16))) unsigned short ekv[8][32][72];  // 36.9 KB

    const int j = blockIdx.x, b = blockIdx.y;
    const int tid = threadIdx.x;
    const int l = tid & 63;
    const int w = tid >> 6;
    const int m = l & 15, hq = l >> 4;

    // persistent A fragments: W_kv rows 128 + 64w + 16tm + m, k = 32kt + 8hq
    s16x8 afr[4][4];
#pragma unroll
    for (int tm = 0; tm < 4; ++tm)
#pragma unroll
        for (int kt = 0; kt < 4; ++kt)
            afr[tm][kt] = *reinterpret_cast<const s16x8*>(
                wbf + (size_t)(CDIM + 64 * w + 16 * tm + m) * CDIM + 32 * kt + 8 * hq);

    f32x4 cacc[2][2] = {};
    float sacc[4][4] = {};
    const float* xc = x + (size_t)b * CDIM * NTOT + j * CHN;
    unsigned int* xsd = (unsigned int*)xsT;

    for (int it = 0; it < CHN / TN; ++it) {
        stage_xT(xc + it * TN, xsd, tid);
        __syncthreads();

        // KV GEMM: acc[tm][tn] rows 64w+16tm+.., cols n = 16tn+m (within subtile)
        f32x4 acc[4][4] = {};
#pragma unroll
        for (int kt = 0; kt < 4; ++kt) {
#pragma unroll
            for (int tn = 0; tn < 4; ++tn) {
                const s16x8 bfr = ld_frag_lds(xsd, (16 * tn + m) * 65 + 16 * kt + 4 * hq);
#pragma unroll
                for (int tm = 0; tm < 4; ++tm)
                    acc[tm][tn] = __builtin_amdgcn_mfma_f32_16x16x32_bf16(
                        afr[tm][kt], bfr, acc[tm][tn], 0, 0, 0);
            }
        }

        // exp(K) -> ekv[0..3], V -> ekv[4..7]; s partials in registers
        if (w < 2) {
#pragma unroll
            for (int tm = 0; tm < 4; ++tm)
#pragma unroll
                for (int tn = 0; tn < 4; ++tn)
#pragma unroll
                    for (int r = 0; r < 4; ++r) {
                        const int dg = 64 * w + 16 * tm + 4 * hq + r;
                        const float e = __expf(acc[tm][tn][r]);
                        sacc[tm][r] += e;
                        ekv[dg >> 5][dg & 31][16 * tn + m] = f2bf(e);
                    }
        } else {
#pragma unroll
            for (int tm = 0; tm < 4; ++tm)
#pragma unroll
                for (int tn = 0; tn < 4; ++tn)
#pragma unroll
                    for (int r = 0; r < 4; ++r) {
                        const int eg = 64 * (w - 2) + 16 * tm + 4 * hq + r;
                        ekv[4 + (eg >> 5)][eg & 31][16 * tn + m] = f2bf(acc[tm][tn][r]);
                    }
        }
        __syncthreads();

        // context MFMA: head = w. A = v rows e, B = ek cols d, contraction n.
#pragma unroll
        for (int kt = 0; kt < 2; ++kt) {
            s16x8 va[2], eb[2];
#pragma unroll
            for (int t = 0; t < 2; ++t) {
                va[t] = *reinterpret_cast<const s16x8*>(
                    &ekv[4 + w][16 * t + m][32 * kt + 8 * hq]);
                eb[t] = *reinterpret_cast<const s16x8*>(
                    &ekv[w][16 * t + m][32 * kt + 8 * hq]);
            }
#pragma unroll
            for (int tm = 0; tm < 2; ++tm)
#pragma unroll
                for (int tn = 0; tn < 2; ++tn)
                    cacc[tm][tn] = __builtin_amdgcn_mfma_f32_16x16x32_bf16(
                        va[tm], eb[tn], cacc[tm][tn], 0, 0, 0);
        }
        __syncthreads();
    }

    // partial C2[e][d] for head w
    float* pc = ws + PC_OFF + (size_t)((b * 4 + w) * NCH + j) * 1024;
#pragma unroll
    for (int tm = 0; tm < 2; ++tm)
#pragma unroll
        for (int tn = 0; tn < 2; ++tn)
#pragma unroll
            for (int r = 0; r < 4; ++r)
                pc[(16 * tm + 4 * hq + r) * 32 + 16 * tn + m] = cacc[tm][tn][r];

    // s: reduce over the 16 columns (lanes m), write once per row
    if (w < 2) {
#pragma unroll
        for (int tm = 0; tm < 4; ++tm)
#pragma unroll
            for (int r = 0; r < 4; ++r) {
                float s = sacc[tm][r];
                s += __shfl_xor(s, 1);
                s += __shfl_xor(s, 2);
                s += __shfl_xor(s, 4);
                s += __shfl_xor(s, 8);
                if (m == 0) {
                    const int dg = 64 * w + 16 * tm + 4 * hq + r;
                    ws[PS_OFF + (size_t)((b * 4 + (dg >> 5)) * NCH + j) * 32 + (dg & 31)] = s;
                }
            }
    }
}

// ---------------------------------------------------------------------------
// k2: merge partials -> ctx[d][e]; M[b] = W_out . BD(ctx) . W_q  -> bf16
// ---------------------------------------------------------------------------
__global__ __launch_bounds__(256)
void k2_buildM(const float* __restrict__ wqkv, const float* __restrict__ wout,
               float* __restrict__ ws) {
    const int b = blockIdx.x, tid = threadIdx.x;
    __shared__ float stot[32];
    __shared__ float ctx[32][33];
    __shared__ float G[CDIM][33];

    float Macc[64] = {};
    const int o = tid >> 1, half = tid & 1;

    for (int h = 0; h < 4; ++h) {
        __syncthreads();
        if (tid < 32) {
            float s = 0.f;
            for (int jj = 0; jj < NCH; ++jj)
                s += ws[PS_OFF + (size_t)((b * 4 + h) * NCH + jj) * 32 + tid];
            stot[tid] = s;
        }
        __syncthreads();
        {
            const size_t base = (size_t)(b * 4 + h) * NCH;
#pragma unroll
            for (int k = 0; k < 4; ++k) {
                const int idx = tid + 256 * k;  // idx = e*32 + d
                float c = 0.f;
                for (int jj = 0; jj < NCH; ++jj)
                    c += ws[PC_OFF + (base + jj) * 1024 + idx];
                ctx[idx & 31][idx >> 5] = c / stot[idx & 31];  // ctx[d][e]
            }
        }
        __syncthreads();
        {
#pragma unroll
            for (int dd = 0; dd < 16; ++dd) {
                const int d = half * 16 + dd;
                float g = 0.f;
#pragma unroll
                for (int e = 0; e < 32; ++e)
                    g = fmaf(wout[o * CDIM + h * 32 + e], ctx[d][e], g);
                G[o][d] = g;
            }
        }
        __syncthreads();
        {
            const int c0 = half * 64;
            for (int d = 0; d < 32; ++d) {
                const float gv = G[o][d];
                const float* wq = wqkv + (size_t)(h * 32 + d) * CDIM + c0;
#pragma unroll
                for (int cc = 0; cc < 64; ++cc)
                    Macc[cc] = fmaf(gv, wq[cc], Macc[cc]);
            }
        }
    }
    unsigned short* mbf = (unsigned short*)(ws + MBF_OFF);
    unsigned short* mp = mbf + (size_t)b * CDIM * CDIM + o * CDIM + half * 64;
#pragma unroll
    for (int cc = 0; cc < 64; ++cc) mp[cc] = f2bf(Macc[cc]);
}

// ---------------------------------------------------------------------------
// k3: out[b] = M_bf16[b] @ x_bf16[b] + b_out   (MFMA)
// wave w owns output rows 32w..32w+31; per subtile 64 n.
// ---------------------------------------------------------------------------
__global__ __launch_bounds__(256)
void k3_final(const float* __restrict__ x, const float* __restrict__ bout,
              const float* __restrict__ ws, float* __restrict__ out) {
    __shared__ __attribute__((aligned(16))) unsigned short xsT[64 * 130];

    const int j = blockIdx.x, b = blockIdx.y;
    const int tid = threadIdx.x, l = tid & 63, w = tid >> 6;
    const int m = l & 15, hq = l >> 4;

    const unsigned short* mbf =
        (const unsigned short*)(ws + MBF_OFF) + (size_t)b * CDIM * CDIM;
    s16x8 afr[2][4];
#pragma unroll
    for (int tm = 0; tm < 2; ++tm)
#pragma unroll
        for (int kt = 0; kt < 4; ++kt)
            afr[tm][kt] = *reinterpret_cast<const s16x8*>(
                mbf + (size_t)(32 * w + 16 * tm + m) * CDIM + 32 * kt + 8 * hq);
    float bias[2][4];
#pragma unroll
    for (int tm = 0; tm < 2; ++tm)
#pragma unroll
        for (int r = 0; r < 4; ++r)
            bias[tm][r] = bout[32 * w + 16 * tm + 4 * hq + r];

    unsigned int* xsd = (unsigned int*)xsT;
    const float* xc = x + (size_t)b * CDIM * NTOT + j * CHN;
    float* oc = out + (size_t)b * CDIM * NTOT + j * CHN;

    for (int it = 0; it < CHN / TN; ++it) {
        stage_xT(xc + it * TN, xsd, tid);
        __syncthreads();
        f32x4 acc[2][4] = {};
#pragma unroll
        for (int kt = 0; kt < 4; ++kt) {
#pragma unroll
            for (int tn = 0; tn < 4; ++tn) {
                const s16x8 bfr = ld_frag_lds(xsd, (16 * tn + m) * 65 + 16 * kt + 4 * hq);
#pragma unroll
                for (int tm = 0; tm < 2; ++tm)
                    acc[tm][tn] = __builtin_amdgcn_mfma_f32_16x16x32_bf16(
                        afr[tm][kt], bfr, acc[tm][tn], 0, 0, 0);
            }
        }
#pragma unroll
        for (int tm = 0; tm < 2; ++tm)
#pragma unroll
            for (int tn = 0; tn < 4; ++tn)
#pragma unroll
                for (int r = 0; r < 4; ++r)
                    oc[(size_t)(32 * w + 16 * tm + 4 * hq + r) * NTOT +
                       it * TN + 16 * tn + m] = acc[tm][tn][r] + bias[tm][r];
        __syncthreads();
    }
}

extern "C" void kernel_launch(void* const* d_in, const int* in_sizes, int n_in,
                              void* d_out, int out_size, void* d_ws, size_t ws_size,
                              hipStream_t stream) {
    const float* x    = (const float*)d_in[0];
    const float* wqkv = (const float*)d_in[1];
    const float* wout = (const float*)d_in[2];
    const float* bout = (const float*)d_in[3];
    float* out = (float*)d_out;
    float* ws  = (float*)d_ws;

    k0_wcvt<<<192, 256, 0, stream>>>(wqkv, ws);
    k1_ctx<<<dim3(NCH, BATCH), 256, 0, stream>>>(
        x, (const unsigned short*)(ws + WBF_OFF), ws);
    k2_buildM<<<BATCH, 256, 0, stream>>>(wqkv, wout, ws);
    k3_final<<<dim3(NCH, BATCH), 256, 0, stream>>>(x, bout, ws, out);
}

// Round 5
// 79.491 us; speedup vs baseline: 12.7716x; 4.6181x over previous
//
#include <hip/hip_runtime.h>
#include <hip/hip_bf16.h>
#include <math.h>

#define BATCH 32
#define CDIM  128
#define NTOT  4096
#define NCH   16           // chunks per batch (k1/k3 grid.x)
#define CHN   256          // n per block
#define TN    64           // n per subtile

typedef __attribute__((ext_vector_type(4))) float f32x4;
typedef __attribute__((ext_vector_type(8))) short s16x8;

// ---- ws layout (float offsets) ----
#define PC_OFF  0
#define PC_SIZE (BATCH * 4 * NCH * 32 * 32)   // partial C2[e][d], 2,097,152 f
#define PS_OFF  (PC_OFF + PC_SIZE)
#define PS_SIZE (BATCH * 4 * NCH * 32)        // partial s[d], 65,536 f
#define WBF_OFF (PS_OFF + PS_SIZE)            // w_qkv bf16: 49,152 u16 = 24,576 f
#define MBF_OFF (WBF_OFF + 24576)             // M bf16: 524,288 u16 = 262,144 f
#define CTX_OFF (MBF_OFF + 262144)            // ctx: 32b*4h*1024 = 131,072 f
// total = 2,580,480 floats = 10.32 MB (R1 used 10.7 MB OK)

static __device__ __forceinline__ unsigned short f2bf(float f) {
    return __builtin_bit_cast(unsigned short, __float2bfloat16(f));
}
static __device__ __forceinline__ unsigned int pack2(float a, float b) {
    return (unsigned int)f2bf(a) | ((unsigned int)f2bf(b) << 16);
}
static __device__ __forceinline__ s16x8 ld_frag_lds(const unsigned int* xsd, int d0) {
    int4 t;
    t.x = (int)xsd[d0]; t.y = (int)xsd[d0 + 1];
    t.z = (int)xsd[d0 + 2]; t.w = (int)xsd[d0 + 3];
    return __builtin_bit_cast(s16x8, t);
}

// Stage a 128c x 64n fp32 tile -> LDS bf16 transposed [n][c], 65 dwords/row.
static __device__ __forceinline__ void stage_xT(const float* __restrict__ xc,
                                                unsigned int* __restrict__ xsd,
                                                int tid) {
    const int m  = tid & 15;
    const int cg = tid >> 4;
#pragma unroll
    for (int p = 0; p < 4; ++p) {
        const int c = 2 * cg + 32 * p;
        const f32x4 a0 = *reinterpret_cast<const f32x4*>(xc + (size_t)c * NTOT + 4 * m);
        const f32x4 a1 = *reinterpret_cast<const f32x4*>(xc + (size_t)(c + 1) * NTOT + 4 * m);
#pragma unroll
        for (int jj = 0; jj < 4; ++jj)
            xsd[(4 * m + jj) * 65 + (c >> 1)] = pack2(a0[jj], a1[jj]);
    }
}

// ---------------------------------------------------------------------------
// k0: convert w_qkv to bf16 in ws
// ---------------------------------------------------------------------------
__global__ void k0_wcvt(const float* __restrict__ wqkv, float* __restrict__ ws) {
    const int i = blockIdx.x * 256 + threadIdx.x;
    unsigned short* wbf = (unsigned short*)(ws + WBF_OFF);
    if (i < 384 * CDIM) wbf[i] = f2bf(wqkv[i]);
}

// ---------------------------------------------------------------------------
// k1: per (chunk j, batch b): KV = W_kv @ x_chunk (MFMA), exp, partial s and
//     C2[e][d] (MFMA from padded LDS).  (unchanged from R2 - verified)
// ---------------------------------------------------------------------------
__global__ __launch_bounds__(256, 2)
void k1_ctx(const float* __restrict__ x, const unsigned short* __restrict__ wbf,
            float* __restrict__ ws) {
    __shared__ __attribute__((aligned(16))) unsigned short xsT[64 * 130];   // 16.6 KB
    __shared__ __attribute__((aligned(16))) unsigned short ekv[8][32][72];  // 36.9 KB

    const int j = blockIdx.x, b = blockIdx.y;
    const int tid = threadIdx.x;
    const int l = tid & 63;
    const int w = tid >> 6;
    const int m = l & 15, hq = l >> 4;

    s16x8 afr[4][4];
#pragma unroll
    for (int tm = 0; tm < 4; ++tm)
#pragma unroll
        for (int kt = 0; kt < 4; ++kt)
            afr[tm][kt] = *reinterpret_cast<const s16x8*>(
                wbf + (size_t)(CDIM + 64 * w + 16 * tm + m) * CDIM + 32 * kt + 8 * hq);

    f32x4 cacc[2][2] = {};
    float sacc[4][4] = {};
    const float* xc = x + (size_t)b * CDIM * NTOT + j * CHN;
    unsigned int* xsd = (unsigned int*)xsT;

    for (int it = 0; it < CHN / TN; ++it) {
        stage_xT(xc + it * TN, xsd, tid);
        __syncthreads();

        f32x4 acc[4][4] = {};
#pragma unroll
        for (int kt = 0; kt < 4; ++kt) {
#pragma unroll
            for (int tn = 0; tn < 4; ++tn) {
                const s16x8 bfr = ld_frag_lds(xsd, (16 * tn + m) * 65 + 16 * kt + 4 * hq);
#pragma unroll
                for (int tm = 0; tm < 4; ++tm)
                    acc[tm][tn] = __builtin_amdgcn_mfma_f32_16x16x32_bf16(
                        afr[tm][kt], bfr, acc[tm][tn], 0, 0, 0);
            }
        }

        if (w < 2) {
#pragma unroll
            for (int tm = 0; tm < 4; ++tm)
#pragma unroll
                for (int tn = 0; tn < 4; ++tn)
#pragma unroll
                    for (int r = 0; r < 4; ++r) {
                        const int dg = 64 * w + 16 * tm + 4 * hq + r;
                        const float e = __expf(acc[tm][tn][r]);
                        sacc[tm][r] += e;
                        ekv[dg >> 5][dg & 31][16 * tn + m] = f2bf(e);
                    }
        } else {
#pragma unroll
            for (int tm = 0; tm < 4; ++tm)
#pragma unroll
                for (int tn = 0; tn < 4; ++tn)
#pragma unroll
                    for (int r = 0; r < 4; ++r) {
                        const int eg = 64 * (w - 2) + 16 * tm + 4 * hq + r;
                        ekv[4 + (eg >> 5)][eg & 31][16 * tn + m] = f2bf(acc[tm][tn][r]);
                    }
        }
        __syncthreads();

#pragma unroll
        for (int kt = 0; kt < 2; ++kt) {
            s16x8 va[2], eb[2];
#pragma unroll
            for (int t = 0; t < 2; ++t) {
                va[t] = *reinterpret_cast<const s16x8*>(
                    &ekv[4 + w][16 * t + m][32 * kt + 8 * hq]);
                eb[t] = *reinterpret_cast<const s16x8*>(
                    &ekv[w][16 * t + m][32 * kt + 8 * hq]);
            }
#pragma unroll
            for (int tm = 0; tm < 2; ++tm)
#pragma unroll
                for (int tn = 0; tn < 2; ++tn)
                    cacc[tm][tn] = __builtin_amdgcn_mfma_f32_16x16x32_bf16(
                        va[tm], eb[tn], cacc[tm][tn], 0, 0, 0);
        }
        __syncthreads();
    }

    float* pc = ws + PC_OFF + (size_t)((b * 4 + w) * NCH + j) * 1024;
#pragma unroll
    for (int tm = 0; tm < 2; ++tm)
#pragma unroll
        for (int tn = 0; tn < 2; ++tn)
#pragma unroll
            for (int r = 0; r < 4; ++r)
                pc[(16 * tm + 4 * hq + r) * 32 + 16 * tn + m] = cacc[tm][tn][r];

    if (w < 2) {
#pragma unroll
        for (int tm = 0; tm < 4; ++tm)
#pragma unroll
            for (int r = 0; r < 4; ++r) {
                float s = sacc[tm][r];
                s += __shfl_xor(s, 1);
                s += __shfl_xor(s, 2);
                s += __shfl_xor(s, 4);
                s += __shfl_xor(s, 8);
                if (m == 0) {
                    const int dg = 64 * w + 16 * tm + 4 * hq + r;
                    ws[PS_OFF + (size_t)((b * 4 + (dg >> 5)) * NCH + j) * 32 + (dg & 31)] = s;
                }
            }
    }
}

// ---------------------------------------------------------------------------
// k2a: merge partials -> normalized ctx in ws. One block per (b,h).
// CTX[b][h][e*32+d] = (sum_j pc[e*32+d]) / stot[d]
// ---------------------------------------------------------------------------
__global__ __launch_bounds__(256)
void k2a_ctx(float* __restrict__ ws) {
    const int bh = blockIdx.x;   // b*4 + h
    const int tid = threadIdx.x;
    __shared__ float stotS[32];
    if (tid < 32) {
        float s = 0.f;
        for (int j = 0; j < NCH; ++j)
            s += ws[PS_OFF + (size_t)(bh * NCH + j) * 32 + tid];
        stotS[tid] = s;
    }
    __syncthreads();
#pragma unroll
    for (int k = 0; k < 4; ++k) {
        const int idx = tid + 256 * k;  // e*32 + d
        float c = 0.f;
        for (int j = 0; j < NCH; ++j)
            c += ws[PC_OFF + (size_t)(bh * NCH + j) * 1024 + idx];
        ws[CTX_OFF + (size_t)bh * 1024 + idx] = c / stotS[idx & 31];
    }
}

// ---------------------------------------------------------------------------
// k2b: M[b] = W_out . BD(ctx) . W_q -> bf16.  grid (4 o-tiles, 32 batches).
// Phase A (LDS: ctxs + wouts): G[o][hd] = sum_e wout[o,h*32+e]*ctx[h][d][e]
// Phase B (LDS reused for W_q bf16): M[o][c] = sum_hd G[o][hd]*wq[hd][c]
// ---------------------------------------------------------------------------
__global__ __launch_bounds__(256)
void k2b_buildM(const float* __restrict__ wout, float* __restrict__ ws) {
    const int oq = blockIdx.x;   // o-tile: rows oq*32 .. +31
    const int b  = blockIdx.y;
    const int tid = threadIdx.x;

    __shared__ __attribute__((aligned(16))) float smA[8704]; // A: ctxs[4224]+wouts[4256]; B: wq dwords[8704]
    __shared__ float G[32][133];                             // 17.0 KB
    float* ctxs  = smA;          // [hd][33] : (h*32+d)*33 + e
    float* wouts = smA + 4224;   // [o][133]
    unsigned int* wqs = (unsigned int*)smA;  // [hd][68] dwords (bf16 pairs)

    // ---- stage ctx (transpose to [hd][e]) and wout rows ----
#pragma unroll
    for (int k = 0; k < 16; ++k) {
        const int fid = tid + 256 * k;          // h*1024 + e*32 + d
        const int h = fid >> 10, rem = fid & 1023;
        const int e = rem >> 5, d = rem & 31;
        ctxs[(h * 32 + d) * 33 + e] = ws[CTX_OFF + (size_t)b * 4096 + fid];
    }
#pragma unroll
    for (int k = 0; k < 16; ++k) {
        const int fid = tid + 256 * k;          // o*128 + c
        const int o = fid >> 7, c = fid & 127;
        wouts[o * 133 + c] = wout[(size_t)(oq * 32 + o) * CDIM + c];
    }
    __syncthreads();

    // ---- phase A: G ----
    {
        const int o2 = tid & 31;
        const int g8 = tid >> 5;   // 0..7
#pragma unroll
        for (int i = 0; i < 16; ++i) {
            const int hd = g8 * 16 + i;
            const int h = hd >> 5;
            float acc = 0.f;
#pragma unroll
            for (int e = 0; e < 32; ++e)
                acc = fmaf(wouts[o2 * 133 + h * 32 + e], ctxs[hd * 33 + e], acc);
            G[o2][hd] = acc;
        }
    }
    __syncthreads();

    // ---- stage W_q (bf16 rows 0..127 of wbf) into reused LDS ----
    {
        const unsigned int* wbfu = (const unsigned int*)(ws + WBF_OFF);
#pragma unroll
        for (int k = 0; k < 32; ++k) {
            const int fid = tid + 256 * k;      // hd*64 + cd
            const int hd = fid >> 6, cd = fid & 63;
            wqs[hd * 68 + cd] = wbfu[fid];
        }
    }
    __syncthreads();

    // ---- phase B: M rows ----
    {
        const int o3 = tid >> 3;        // 0..31
        const int c0 = tid & 7;         // c = c0*16 + i
        float Macc[16];
#pragma unroll
        for (int i = 0; i < 16; ++i) Macc[i] = 0.f;
        for (int hd = 0; hd < 128; ++hd) {
            const float gv = G[o3][hd];
            const uint4 w0 = *reinterpret_cast<const uint4*>(&wqs[hd * 68 + c0 * 8]);
            const uint4 w1 = *reinterpret_cast<const uint4*>(&wqs[hd * 68 + c0 * 8 + 4]);
            const unsigned int dw[8] = {w0.x, w0.y, w0.z, w0.w, w1.x, w1.y, w1.z, w1.w};
#pragma unroll
            for (int q = 0; q < 8; ++q) {
                const float lo = __builtin_bit_cast(float, dw[q] << 16);
                const float hi = __builtin_bit_cast(float, dw[q] & 0xffff0000u);
                Macc[2 * q]     = fmaf(gv, lo, Macc[2 * q]);
                Macc[2 * q + 1] = fmaf(gv, hi, Macc[2 * q + 1]);
            }
        }
        // pack + store 32B
        unsigned int* mpd = (unsigned int*)((unsigned short*)(ws + MBF_OFF) +
                                            (size_t)b * CDIM * CDIM) +
                            (oq * 32 + o3) * 64 + c0 * 8;
        uint4 s0, s1;
        s0.x = pack2(Macc[0], Macc[1]);   s0.y = pack2(Macc[2], Macc[3]);
        s0.z = pack2(Macc[4], Macc[5]);   s0.w = pack2(Macc[6], Macc[7]);
        s1.x = pack2(Macc[8], Macc[9]);   s1.y = pack2(Macc[10], Macc[11]);
        s1.z = pack2(Macc[12], Macc[13]); s1.w = pack2(Macc[14], Macc[15]);
        *reinterpret_cast<uint4*>(mpd) = s0;
        *reinterpret_cast<uint4*>(mpd + 4) = s1;
    }
}

// ---------------------------------------------------------------------------
// k3: out[b] = M_bf16[b] @ x_bf16[b] + b_out   (MFMA, unchanged from R2)
// ---------------------------------------------------------------------------
__global__ __launch_bounds__(256)
void k3_final(const float* __restrict__ x, const float* __restrict__ bout,
              const float* __restrict__ ws, float* __restrict__ out) {
    __shared__ __attribute__((aligned(16))) unsigned short xsT[64 * 130];

    const int j = blockIdx.x, b = blockIdx.y;
    const int tid = threadIdx.x, l = tid & 63, w = tid >> 6;
    const int m = l & 15, hq = l >> 4;

    const unsigned short* mbf =
        (const unsigned short*)(ws + MBF_OFF) + (size_t)b * CDIM * CDIM;
    s16x8 afr[2][4];
#pragma unroll
    for (int tm = 0; tm < 2; ++tm)
#pragma unroll
        for (int kt = 0; kt < 4; ++kt)
            afr[tm][kt] = *reinterpret_cast<const s16x8*>(
                mbf + (size_t)(32 * w + 16 * tm + m) * CDIM + 32 * kt + 8 * hq);
    float bias[2][4];
#pragma unroll
    for (int tm = 0; tm < 2; ++tm)
#pragma unroll
        for (int r = 0; r < 4; ++r)
            bias[tm][r] = bout[32 * w + 16 * tm + 4 * hq + r];

    unsigned int* xsd = (unsigned int*)xsT;
    const float* xc = x + (size_t)b * CDIM * NTOT + j * CHN;
    float* oc = out + (size_t)b * CDIM * NTOT + j * CHN;

    for (int it = 0; it < CHN / TN; ++it) {
        stage_xT(xc + it * TN, xsd, tid);
        __syncthreads();
        f32x4 acc[2][4] = {};
#pragma unroll
        for (int kt = 0; kt < 4; ++kt) {
#pragma unroll
            for (int tn = 0; tn < 4; ++tn) {
                const s16x8 bfr = ld_frag_lds(xsd, (16 * tn + m) * 65 + 16 * kt + 4 * hq);
#pragma unroll
                for (int tm = 0; tm < 2; ++tm)
                    acc[tm][tn] = __builtin_amdgcn_mfma_f32_16x16x32_bf16(
                        afr[tm][kt], bfr, acc[tm][tn], 0, 0, 0);
            }
        }
#pragma unroll
        for (int tm = 0; tm < 2; ++tm)
#pragma unroll
            for (int tn = 0; tn < 4; ++tn)
#pragma unroll
                for (int r = 0; r < 4; ++r)
                    oc[(size_t)(32 * w + 16 * tm + 4 * hq + r) * NTOT +
                       it * TN + 16 * tn + m] = acc[tm][tn][r] + bias[tm][r];
        __syncthreads();
    }
}

extern "C" void kernel_launch(void* const* d_in, const int* in_sizes, int n_in,
                              void* d_out, int out_size, void* d_ws, size_t ws_size,
                              hipStream_t stream) {
    const float* x    = (const float*)d_in[0];
    const float* wqkv = (const float*)d_in[1];
    const float* wout = (const float*)d_in[2];
    const float* bout = (const float*)d_in[3];
    float* out = (float*)d_out;
    float* ws  = (float*)d_ws;

    k0_wcvt<<<192, 256, 0, stream>>>(wqkv, ws);
    k1_ctx<<<dim3(NCH, BATCH), 256, 0, stream>>>(
        x, (const unsigned short*)(ws + WBF_OFF), ws);
    k2a_ctx<<<BATCH * 4, 256, 0, stream>>>(ws);
    k2b_buildM<<<dim3(4, BATCH), 256, 0, stream>>>(wout, ws);
    k3_final<<<dim3(NCH, BATCH), 256, 0, stream>>>(x, bout, ws, out);
}

// Round 6
// 78.048 us; speedup vs baseline: 13.0078x; 1.0185x over previous
//
#include <hip/hip_runtime.h>
#include <hip/hip_bf16.h>
#include <math.h>

#define BATCH 32
#define CDIM  128
#define NTOT  4096
#define NCH   16           // chunks per batch (k1/k3 grid.x)
#define CHN   256          // n per block
#define TN    64           // n per subtile

typedef __attribute__((ext_vector_type(4))) float f32x4;
typedef __attribute__((ext_vector_type(8))) short s16x8;

// ---- ws layout (float offsets) ----
#define PC_OFF  0
#define PC_SIZE (BATCH * 4 * NCH * 32 * 32)   // 2,097,152 f
#define PS_OFF  (PC_OFF + PC_SIZE)
#define PS_SIZE (BATCH * 4 * NCH * 32)        // 65,536 f
#define MBF_OFF (PS_OFF + PS_SIZE)            // M bf16: 524,288 u16 = 262,144 f
#define MBF_SIZE (BATCH * CDIM * CDIM / 2)
#define XBT_OFF (MBF_OFF + MBF_SIZE)          // x bf16 transposed tiles: 8,388,608 f
#define XBT_SIZE (BATCH * CDIM * NTOT / 2)
#define NEED_BYTES ((size_t)(XBT_OFF + XBT_SIZE) * 4)   // 43,253,760 B

static __device__ __forceinline__ unsigned short f2bf(float f) {
    return __builtin_bit_cast(unsigned short, __float2bfloat16(f));
}
static __device__ __forceinline__ unsigned int pack2(float a, float b) {
    return (unsigned int)f2bf(a) | ((unsigned int)f2bf(b) << 16);
}
static __device__ __forceinline__ s16x8 ld_frag_lds(const unsigned int* xsd, int d0) {
    int4 t;
    t.x = (int)xsd[d0]; t.y = (int)xsd[d0 + 1];
    t.z = (int)xsd[d0 + 2]; t.w = (int)xsd[d0 + 3];
    return __builtin_bit_cast(s16x8, t);
}

// Stage a 128c x 64n fp32 tile -> LDS bf16 transposed [n][c], 65 dwords/row.
static __device__ __forceinline__ void stage_xT(const float* __restrict__ xc,
                                                unsigned int* __restrict__ xsd,
                                                int tid) {
    const int m  = tid & 15;
    const int cg = tid >> 4;
#pragma unroll
    for (int p = 0; p < 4; ++p) {
        const int c = 2 * cg + 32 * p;
        const f32x4 a0 = *reinterpret_cast<const f32x4*>(xc + (size_t)c * NTOT + 4 * m);
        const f32x4 a1 = *reinterpret_cast<const f32x4*>(xc + (size_t)(c + 1) * NTOT + 4 * m);
#pragma unroll
        for (int jj = 0; jj < 4; ++jj)
            xsd[(4 * m + jj) * 65 + (c >> 1)] = pack2(a0[jj], a1[jj]);
    }
}

// ---------------------------------------------------------------------------
// k1: KV = W_kv @ x_chunk (MFMA, inline fp32->bf16 weight cvt), exp, partials.
// If XBT: also persist the transposed bf16 x tiles (XOR-swizzled) for k3.
// ---------------------------------------------------------------------------
template <bool XBT>
__global__ __launch_bounds__(256, 2)
void k1_ctx(const float* __restrict__ x, const float* __restrict__ wqkv,
            float* __restrict__ ws) {
    __shared__ __attribute__((aligned(16))) unsigned short xsT[64 * 130];   // 16.6 KB
    __shared__ __attribute__((aligned(16))) unsigned short ekv[8][32][72];  // 36.9 KB

    const int j = blockIdx.x, b = blockIdx.y;
    const int tid = threadIdx.x;
    const int l = tid & 63;
    const int w = tid >> 6;
    const int m = l & 15, hq = l >> 4;

    // persistent A fragments: W_kv rows 128 + 64w + 16tm + m, k = 32kt + 8hq
    // inline fp32->bf16 (bitwise same values as the old k0 conversion)
    s16x8 afr[4][4];
#pragma unroll
    for (int tm = 0; tm < 4; ++tm)
#pragma unroll
        for (int kt = 0; kt < 4; ++kt) {
            const float* wr = wqkv +
                (size_t)(CDIM + 64 * w + 16 * tm + m) * CDIM + 32 * kt + 8 * hq;
            const f32x4 u0 = *reinterpret_cast<const f32x4*>(wr);
            const f32x4 u1 = *reinterpret_cast<const f32x4*>(wr + 4);
            int4 t4;
            t4.x = (int)pack2(u0[0], u0[1]); t4.y = (int)pack2(u0[2], u0[3]);
            t4.z = (int)pack2(u1[0], u1[1]); t4.w = (int)pack2(u1[2], u1[3]);
            afr[tm][kt] = __builtin_bit_cast(s16x8, t4);
        }

    f32x4 cacc[2][2] = {};
    float sacc[4][4] = {};
    const float* xc = x + (size_t)b * CDIM * NTOT + j * CHN;
    unsigned int* xsd = (unsigned int*)xsT;

    for (int it = 0; it < CHN / TN; ++it) {
        stage_xT(xc + it * TN, xsd, tid);
        __syncthreads();

        // persist swizzled bf16 tile for k3 (linear global rows of 64 dwords;
        // value at (n, cd) = padded-LDS (n, cd ^ ((n&7)<<2)))
        if constexpr (XBT) {
            unsigned int* tb = (unsigned int*)(ws + XBT_OFF) +
                               ((size_t)(b * NCH + j) * 4 + it) * 4096;
            const int n = tid >> 2, qt = tid & 3;
#pragma unroll
            for (int p = 0; p < 4; ++p) {
                const int cdl = 16 * p + 4 * qt;
                const int src = n * 65 + (cdl ^ ((n & 7) << 2));
                uint4 v;
                v.x = xsd[src]; v.y = xsd[src + 1];
                v.z = xsd[src + 2]; v.w = xsd[src + 3];
                *reinterpret_cast<uint4*>(tb + (size_t)n * 64 + cdl) = v;
            }
        }

        // KV GEMM
        f32x4 acc[4][4] = {};
#pragma unroll
        for (int kt = 0; kt < 4; ++kt) {
#pragma unroll
            for (int tn = 0; tn < 4; ++tn) {
                const s16x8 bfr = ld_frag_lds(xsd, (16 * tn + m) * 65 + 16 * kt + 4 * hq);
#pragma unroll
                for (int tm = 0; tm < 4; ++tm)
                    acc[tm][tn] = __builtin_amdgcn_mfma_f32_16x16x32_bf16(
                        afr[tm][kt], bfr, acc[tm][tn], 0, 0, 0);
            }
        }

        // exp(K) -> ekv[0..3], V -> ekv[4..7]; s partials in registers
        if (w < 2) {
#pragma unroll
            for (int tm = 0; tm < 4; ++tm)
#pragma unroll
                for (int tn = 0; tn < 4; ++tn)
#pragma unroll
                    for (int r = 0; r < 4; ++r) {
                        const int dg = 64 * w + 16 * tm + 4 * hq + r;
                        const float e = __expf(acc[tm][tn][r]);
                        sacc[tm][r] += e;
                        ekv[dg >> 5][dg & 31][16 * tn + m] = f2bf(e);
                    }
        } else {
#pragma unroll
            for (int tm = 0; tm < 4; ++tm)
#pragma unroll
                for (int tn = 0; tn < 4; ++tn)
#pragma unroll
                    for (int r = 0; r < 4; ++r) {
                        const int eg = 64 * (w - 2) + 16 * tm + 4 * hq + r;
                        ekv[4 + (eg >> 5)][eg & 31][16 * tn + m] = f2bf(acc[tm][tn][r]);
                    }
        }
        __syncthreads();

        // context MFMA: head = w
#pragma unroll
        for (int kt = 0; kt < 2; ++kt) {
            s16x8 va[2], eb[2];
#pragma unroll
            for (int t = 0; t < 2; ++t) {
                va[t] = *reinterpret_cast<const s16x8*>(
                    &ekv[4 + w][16 * t + m][32 * kt + 8 * hq]);
                eb[t] = *reinterpret_cast<const s16x8*>(
                    &ekv[w][16 * t + m][32 * kt + 8 * hq]);
            }
#pragma unroll
            for (int tm = 0; tm < 2; ++tm)
#pragma unroll
                for (int tn = 0; tn < 2; ++tn)
                    cacc[tm][tn] = __builtin_amdgcn_mfma_f32_16x16x32_bf16(
                        va[tm], eb[tn], cacc[tm][tn], 0, 0, 0);
        }
        __syncthreads();
    }

    float* pc = ws + PC_OFF + (size_t)((b * 4 + w) * NCH + j) * 1024;
#pragma unroll
    for (int tm = 0; tm < 2; ++tm)
#pragma unroll
        for (int tn = 0; tn < 2; ++tn)
#pragma unroll
            for (int r = 0; r < 4; ++r)
                pc[(16 * tm + 4 * hq + r) * 32 + 16 * tn + m] = cacc[tm][tn][r];

    if (w < 2) {
#pragma unroll
        for (int tm = 0; tm < 4; ++tm)
#pragma unroll
            for (int r = 0; r < 4; ++r) {
                float s = sacc[tm][r];
                s += __shfl_xor(s, 1);
                s += __shfl_xor(s, 2);
                s += __shfl_xor(s, 4);
                s += __shfl_xor(s, 8);
                if (m == 0) {
                    const int dg = 64 * w + 16 * tm + 4 * hq + r;
                    ws[PS_OFF + (size_t)((b * 4 + (dg >> 5)) * NCH + j) * 32 + (dg & 31)] = s;
                }
            }
    }
}

// ---------------------------------------------------------------------------
// k2: merged k2a+k2b. grid (4 o-tiles, 32 batches).
// Per block: merge partials -> ctx (redundant x4, L2-resident), then
// G = W_out.ctx (phase A), M = G.W_q (phase B, inline W_q cvt), -> bf16 M.
// ---------------------------------------------------------------------------
__global__ __launch_bounds__(256)
void k2_buildM(const float* __restrict__ wqkv, const float* __restrict__ wout,
               float* __restrict__ ws) {
    const int oq = blockIdx.x;   // o-tile: rows oq*32 .. +31
    const int b  = blockIdx.y;
    const int tid = threadIdx.x;

    __shared__ __attribute__((aligned(16))) float smA[8704];
    __shared__ float G[32][133];
    __shared__ float stotS[128];
    float* ctxs  = smA;          // [hd][33] : (h*32+d)*33 + e
    float* wouts = smA + 4224;   // [o][133]
    unsigned int* wqs = (unsigned int*)smA;  // [hd][68] dwords (bf16 pairs)

    // ---- stot merge (order matches old k2a: j ascending) ----
    if (tid < 128) {
        const int h = tid >> 5, d = tid & 31;
        float s = 0.f;
        for (int j = 0; j < NCH; ++j)
            s += ws[PS_OFF + (size_t)((b * 4 + h) * NCH + j) * 32 + d];
        stotS[tid] = s;
    }
    __syncthreads();

    // ---- ctx merge (transposed into [hd][e]) + wout staging ----
#pragma unroll
    for (int k = 0; k < 16; ++k) {
        const int fid = tid + 256 * k;          // h*1024 + e*32 + d
        const int h = fid >> 10, rem = fid & 1023;
        const int e = rem >> 5, d = rem & 31;
        float c = 0.f;
        for (int j = 0; j < NCH; ++j)
            c += ws[PC_OFF + (size_t)((b * 4 + h) * NCH + j) * 1024 + rem];
        ctxs[(h * 32 + d) * 33 + e] = c / stotS[h * 32 + d];
    }
#pragma unroll
    for (int k = 0; k < 16; ++k) {
        const int fid = tid + 256 * k;          // o*128 + c
        const int o = fid >> 7, c = fid & 127;
        wouts[o * 133 + c] = wout[(size_t)(oq * 32 + o) * CDIM + c];
    }
    __syncthreads();

    // ---- phase A: G[o][hd] = sum_e wout[o, h*32+e] * ctx[h][d][e] ----
    {
        const int o2 = tid & 31;
        const int g8 = tid >> 5;   // 0..7
#pragma unroll
        for (int i = 0; i < 16; ++i) {
            const int hd = g8 * 16 + i;
            const int h = hd >> 5;
            float acc = 0.f;
#pragma unroll
            for (int e = 0; e < 32; ++e)
                acc = fmaf(wouts[o2 * 133 + h * 32 + e], ctxs[hd * 33 + e], acc);
            G[o2][hd] = acc;
        }
    }
    __syncthreads();

    // ---- stage W_q into reused LDS (inline fp32->bf16, same values as old) ----
    {
#pragma unroll
        for (int k = 0; k < 32; ++k) {
            const int fid = tid + 256 * k;      // hd*64 + cd
            const int hd = fid >> 6, cd = fid & 63;
            const float2 wv =
                *reinterpret_cast<const float2*>(wqkv + (size_t)hd * CDIM + 2 * cd);
            wqs[hd * 68 + cd] = pack2(wv.x, wv.y);
        }
    }
    __syncthreads();

    // ---- phase B: M[o][c] = sum_hd G[o][hd] * wq[hd][c] ----
    {
        const int o3 = tid >> 3;        // 0..31
        const int c0 = tid & 7;
        float Macc[16];
#pragma unroll
        for (int i = 0; i < 16; ++i) Macc[i] = 0.f;
        for (int hd = 0; hd < 128; ++hd) {
            const float gv = G[o3][hd];
            const uint4 w0 = *reinterpret_cast<const uint4*>(&wqs[hd * 68 + c0 * 8]);
            const uint4 w1 = *reinterpret_cast<const uint4*>(&wqs[hd * 68 + c0 * 8 + 4]);
            const unsigned int dw[8] = {w0.x, w0.y, w0.z, w0.w, w1.x, w1.y, w1.z, w1.w};
#pragma unroll
            for (int q = 0; q < 8; ++q) {
                const float lo = __builtin_bit_cast(float, dw[q] << 16);
                const float hi = __builtin_bit_cast(float, dw[q] & 0xffff0000u);
                Macc[2 * q]     = fmaf(gv, lo, Macc[2 * q]);
                Macc[2 * q + 1] = fmaf(gv, hi, Macc[2 * q + 1]);
            }
        }
        unsigned int* mpd = (unsigned int*)((unsigned short*)(ws + MBF_OFF) +
                                            (size_t)b * CDIM * CDIM) +
                            (oq * 32 + o3) * 64 + c0 * 8;
        uint4 s0, s1;
        s0.x = pack2(Macc[0], Macc[1]);   s0.y = pack2(Macc[2], Macc[3]);
        s0.z = pack2(Macc[4], Macc[5]);   s0.w = pack2(Macc[6], Macc[7]);
        s1.x = pack2(Macc[8], Macc[9]);   s1.y = pack2(Macc[10], Macc[11]);
        s1.z = pack2(Macc[12], Macc[13]); s1.w = pack2(Macc[14], Macc[15]);
        *reinterpret_cast<uint4*>(mpd) = s0;
        *reinterpret_cast<uint4*>(mpd + 4) = s1;
    }
}

// ---------------------------------------------------------------------------
// k3: out[b] = M_bf16[b] @ x_bf16[b] + b_out.
// XBT: stage pre-swizzled bf16 tiles with a linear uint4 copy, read b128
// fragments at XOR-swizzled offsets. Else: R5 path (fp32 re-read + transpose).
// ---------------------------------------------------------------------------
template <bool XBT>
__global__ __launch_bounds__(256)
void k3_final(const float* __restrict__ x, const float* __restrict__ bout,
              const float* __restrict__ ws, float* __restrict__ out) {
    __shared__ __attribute__((aligned(16))) unsigned short xsT[64 * 130];

    const int j = blockIdx.x, b = blockIdx.y;
    const int tid = threadIdx.x, l = tid & 63, w = tid >> 6;
    const int m = l & 15, hq = l >> 4;

    const unsigned short* mbf =
        (const unsigned short*)(ws + MBF_OFF) + (size_t)b * CDIM * CDIM;
    s16x8 afr[2][4];
#pragma unroll
    for (int tm = 0; tm < 2; ++tm)
#pragma unroll
        for (int kt = 0; kt < 4; ++kt)
            afr[tm][kt] = *reinterpret_cast<const s16x8*>(
                mbf + (size_t)(32 * w + 16 * tm + m) * CDIM + 32 * kt + 8 * hq);
    float bias[2][4];
#pragma unroll
    for (int tm = 0; tm < 2; ++tm)
#pragma unroll
        for (int r = 0; r < 4; ++r)
            bias[tm][r] = bout[32 * w + 16 * tm + 4 * hq + r];

    unsigned int* xsd = (unsigned int*)xsT;
    const float* xc = x + (size_t)b * CDIM * NTOT + j * CHN;
    float* oc = out + (size_t)b * CDIM * NTOT + j * CHN;

    for (int it = 0; it < CHN / TN; ++it) {
        if constexpr (XBT) {
            const unsigned int* tb = (const unsigned int*)(ws + XBT_OFF) +
                                     ((size_t)(b * NCH + j) * 4 + it) * 4096;
#pragma unroll
            for (int rep = 0; rep < 4; ++rep) {
                const int dw = rep * 1024 + tid * 4;
                *reinterpret_cast<uint4*>(&xsd[dw]) =
                    *reinterpret_cast<const uint4*>(tb + dw);
            }
        } else {
            stage_xT(xc + it * TN, xsd, tid);
        }
        __syncthreads();

        f32x4 acc[2][4] = {};
#pragma unroll
        for (int kt = 0; kt < 4; ++kt) {
#pragma unroll
            for (int tn = 0; tn < 4; ++tn) {
                const int nl = 16 * tn + m;
                s16x8 bfr;
                if constexpr (XBT) {
                    const int idx = nl * 64 + ((16 * kt + 4 * hq) ^ ((nl & 7) << 2));
                    bfr = __builtin_bit_cast(
                        s16x8, *reinterpret_cast<const int4*>(&xsd[idx]));
                } else {
                    bfr = ld_frag_lds(xsd, nl * 65 + 16 * kt + 4 * hq);
                }
#pragma unroll
                for (int tm = 0; tm < 2; ++tm)
                    acc[tm][tn] = __builtin_amdgcn_mfma_f32_16x16x32_bf16(
                        afr[tm][kt], bfr, acc[tm][tn], 0, 0, 0);
            }
        }
#pragma unroll
        for (int tm = 0; tm < 2; ++tm)
#pragma unroll
            for (int tn = 0; tn < 4; ++tn)
#pragma unroll
                for (int r = 0; r < 4; ++r)
                    oc[(size_t)(32 * w + 16 * tm + 4 * hq + r) * NTOT +
                       it * TN + 16 * tn + m] = acc[tm][tn][r] + bias[tm][r];
        __syncthreads();
    }
}

extern "C" void kernel_launch(void* const* d_in, const int* in_sizes, int n_in,
                              void* d_out, int out_size, void* d_ws, size_t ws_size,
                              hipStream_t stream) {
    const float* x    = (const float*)d_in[0];
    const float* wqkv = (const float*)d_in[1];
    const float* wout = (const float*)d_in[2];
    const float* bout = (const float*)d_in[3];
    float* out = (float*)d_out;
    float* ws  = (float*)d_ws;

    const bool xbt = ws_size >= NEED_BYTES;  // deterministic path choice

    if (xbt)
        k1_ctx<true><<<dim3(NCH, BATCH), 256, 0, stream>>>(x, wqkv, ws);
    else
        k1_ctx<false><<<dim3(NCH, BATCH), 256, 0, stream>>>(x, wqkv, ws);

    k2_buildM<<<dim3(4, BATCH), 256, 0, stream>>>(wqkv, wout, ws);

    if (xbt)
        k3_final<true><<<dim3(NCH, BATCH), 256, 0, stream>>>(x, bout, ws, out);
    else
        k3_final<false><<<dim3(NCH, BATCH), 256, 0, stream>>>(x, bout, ws, out);
}